// Round 5
// baseline (10200.935 us; speedup 1.0000x reference)
//
#include <hip/hip_runtime.h>

typedef unsigned short u16;
typedef unsigned long long u64;
typedef __bf16 v8bf __attribute__((ext_vector_type(8)));
typedef float f32x4 __attribute__((ext_vector_type(4)));
typedef u16 u16x4 __attribute__((ext_vector_type(4)));

#define H5 1280
#define TT 512
#define NBLK 80
#define SPL 81920  // u16 elems per split buffer (64*1280)

// ws layout (bytes)
#define OFF_W0 0
#define OFF_W1 3276800
#define OFF_W2 6553600
#define OFF_HS 9830400   // u16 [2][3][64][1280]
#define OFF_WIN 10813440 // float [4][256]
#define OFF_CNT 10817536 // barrier counter

#define MFMA(a, b, c) __builtin_amdgcn_mfma_f32_16x16x32_bf16(a, b, c, 0, 0, 0)

__device__ __forceinline__ float htanh_(float x) {
  return fminf(fmaxf(x, 1e-10f), 1.0f);
}
__device__ __forceinline__ u16 f2b(float f) {
  unsigned u = __float_as_uint(f);
  return (u16)((u + 0x7fffu + ((u >> 16) & 1u)) >> 16);  // RNE
}
__device__ __forceinline__ float b2f(u16 b) {
  return __uint_as_float(((unsigned)b) << 16);
}

// agent-coherent 16B load as 2x8B relaxed atomics (compiler manages waits;
// lowers to global_load_dwordx2 sc0 sc1 — bypasses stale per-XCD L2)
__device__ __forceinline__ v8bf ald16(const u16* p) {
  union { u64 q[2]; v8bf v; } u;
  u.q[0] = __hip_atomic_load((const u64*)p, __ATOMIC_RELAXED, __HIP_MEMORY_SCOPE_AGENT);
  u.q[1] = __hip_atomic_load((const u64*)(p + 4), __ATOMIC_RELAXED, __HIP_MEMORY_SCOPE_AGENT);
  return u.v;
}
// agent-coherent 8B store (write-through to coherence point)
__device__ __forceinline__ void sth(u16* p, u16x4 v) {
  union { u16x4 s; u64 q; } u;
  u.s = v;
  __hip_atomic_store((u64*)p, u.q, __ATOMIC_RELAXED, __HIP_MEMORY_SCOPE_AGENT);
}

// ---------------- prep: effective W_rec, 3-way bf16 split -------------------
__global__ void build_w(const float* __restrict__ w_str2snr, const float* __restrict__ w_m12m1,
                        const float* __restrict__ w_m12str, const float* __restrict__ w_thal2m1,
                        const float* __restrict__ w_m12thal, const float* __restrict__ w_thal2str,
                        const float* __restrict__ w_str2stn, const float* __restrict__ w_snr2thal,
                        const float* __restrict__ fixedw, u16* __restrict__ W0,
                        u16* __restrict__ W1, u16* __restrict__ W2) {
  int idx = blockIdx.x * 256 + threadIdx.x;  // j*1280 + k
  if (idx >= H5 * H5) return;
  int j = idx / H5, k = idx - j * H5;
  int jr = j >> 8, kr = k >> 8, kk = k & 255;
  int o = (j & 255) * 256 + kk;
  float w = 0.0f;
  if (jr == 0) {
    if (kr == 0) w = -fixedw[o];  // str2str_mask==0 -> -(fixed)
    else if (kr == 3) w = htanh_(w_thal2str[o]);
    else if (kr == 4) w = (kk < 180) ? htanh_(w_m12str[o]) : 0.0f;  // n_inhib=76
  } else if (jr == 1) {
    if (kr == 0) w = (kk >= 128) ? htanh_(w_str2stn[o]) : 0.0f;
  } else if (jr == 2) {
    if (kr == 0) w = (kk < 128) ? -htanh_(w_str2snr[o]) : 0.0f;
    else if (kr == 1) w = -htanh_(w_str2stn[o]);  // faithful: str2stn weight
  } else if (jr == 3) {
    if (kr == 2) w = -htanh_(w_snr2thal[o]);
    else if (kr == 4) w = htanh_(w_m12thal[o]);
  } else {
    if (kr == 3) w = htanh_(w_thal2m1[o]);
    else if (kr == 4) w = (kk < 180) ? htanh_(w_m12m1[o]) : -htanh_(w_m12m1[o]);
  }
  u16 c0 = f2b(w);  float r1 = w - b2f(c0);
  u16 c1 = f2b(r1); float r2 = r1 - b2f(c1);
  u16 c2 = f2b(r2);
  W0[idx] = c0; W1[idx] = c1; W2[idx] = c2;
}

// ---------------- prep: mean/std out, h0 splits, Win ------------------------
__global__ void build_misc(const float* __restrict__ hn, const float* __restrict__ inp_weight,
                           const float* __restrict__ mean_b, const float* __restrict__ std_b,
                           float* __restrict__ out, u16* __restrict__ hs, float* __restrict__ Win) {
  int gid = blockIdx.x * 256 + threadIdx.x;
  if (gid < 65536) {
    out[gid] = (gid < 32768) ? mean_b[0] : fminf(10.0f, fmaxf(-5.0f, std_b[0]));
  } else if (gid < 65536 + SPL) {
    int i = gid - 65536;
    float v = hn[i];
    u16 c0 = f2b(v);  float r1 = v - b2f(c0);
    u16 c1 = f2b(r1); float r2 = r1 - b2f(c1);
    u16 c2 = f2b(r2);
    hs[i] = c0; hs[SPL + i] = c1; hs[2 * SPL + i] = c2;
  } else if (gid < 65536 + SPL + 1024) {
    int i = gid - 65536 - SPL;
    Win[i] = htanh_(inp_weight[(i >> 8) * H5 + 768 + (i & 255)]);
  }
}

// ---------------- compile-time region configs -------------------------------
template <int R> struct RC;
template <> struct RC<0> { static constexpr int kb[3] = {0, 768, 1024}; static constexpr int nch[3] = {8, 8, 8}; };
template <> struct RC<1> { static constexpr int kb[3] = {128, 0, 0};    static constexpr int nch[3] = {4, 0, 0}; };
template <> struct RC<2> { static constexpr int kb[3] = {0, 256, 0};    static constexpr int nch[3] = {4, 8, 0}; };
template <> struct RC<3> { static constexpr int kb[3] = {512, 1024, 0}; static constexpr int nch[3] = {8, 8, 0}; };
template <> struct RC<4> { static constexpr int kb[3] = {768, 1024, 0}; static constexpr int nch[3] = {8, 8, 0}; };

// One step's matmul for this wave's (j-tile, b-tile). W fragments stream from
// L2 as plain cached loads (immutable); h splits via agent-coherent loads.
// All per-step register lifetimes are a <=8-chunk window — no persistent
// arrays, no spill pressure.
template <int R>
__device__ __forceinline__ f32x4 do_mm(const u16* __restrict__ hs_r, int b, int lk,
                                       const u16* __restrict__ w0r, const u16* __restrict__ w1r,
                                       const u16* __restrict__ w2r) {
  f32x4 A00 = {0.f, 0.f, 0.f, 0.f}, A01 = {0.f, 0.f, 0.f, 0.f}, A02 = {0.f, 0.f, 0.f, 0.f};
  f32x4 A10 = {0.f, 0.f, 0.f, 0.f}, A11 = {0.f, 0.f, 0.f, 0.f}, A20 = {0.f, 0.f, 0.f, 0.f};
#pragma unroll
  for (int q = 0; q < 3; ++q) {
    if (RC<R>::nch[q] > 0) {
      const int kbq = RC<R>::kb[q];
      const u16* hb = hs_r + (long)b * H5 + kbq + lk;
#pragma unroll
      for (int c = 0; c < RC<R>::nch[q]; ++c) {
        v8bf h0 = ald16(hb + c * 32);
        v8bf h1 = ald16(hb + SPL + c * 32);
        v8bf h2 = ald16(hb + 2 * SPL + c * 32);
        v8bf a0 = *(const v8bf*)(w0r + kbq + c * 32);
        v8bf a1 = *(const v8bf*)(w1r + kbq + c * 32);
        v8bf a2 = *(const v8bf*)(w2r + kbq + c * 32);
        // 6-term split product: W0h0+W0h1+W0h2 + W1h0+W1h1 + W2h0
        A00 = MFMA(a0, h0, A00);
        A01 = MFMA(a0, h1, A01);
        A02 = MFMA(a0, h2, A02);
        A10 = MFMA(a1, h0, A10);
        A11 = MFMA(a1, h1, A11);
        A20 = MFMA(a2, h0, A20);
      }
    }
  }
  f32x4 acc;
#pragma unroll
  for (int rr = 0; rr < 4; ++rr)
    acc[rr] = ((A00[rr] + A10[rr]) + (A01[rr] + A11[rr])) + (A02[rr] + A20[rr]);
  return acc;
}

// ---------------- persistent cooperative worker (per region) ----------------
template <int R>
__device__ void pers_loop(int j0, int b, int lr, int hi, int lk,
                          const float* __restrict__ inp_b, const float* __restrict__ hn,
                          const u16* __restrict__ W0, const u16* __restrict__ W1,
                          const u16* __restrict__ W2, u16* __restrict__ hs,
                          float* __restrict__ rnn_b, float* __restrict__ hn_last,
                          const float* __restrict__ Win, unsigned* __restrict__ counter) {
  const long jrow = (long)(j0 + lr) * H5 + lk;
  const u16* w0r = W0 + jrow;
  const u16* w1r = W1 + jrow;
  const u16* w2r = W2 + jrow;

  float winreg[4][4];
  if constexpr (R == 3) {
#pragma unroll
    for (int i = 0; i < 4; ++i)
#pragma unroll
      for (int rr = 0; rr < 4; ++rr)
        winreg[i][rr] = Win[i * 256 + (j0 - 768) + hi * 4 + rr];
  }

  f32x4 hprev;
  {
    const float* hp = hn + (long)b * H5 + j0 + hi * 4;
#pragma unroll
    for (int rr = 0; rr < 4; ++rr) hprev[rr] = hp[rr];
  }

  const u64 ca = (u64)counter;

  for (int t = 0; t < TT; ++t) {
    const u16* hs_r = hs + (t & 1) * (3 * SPL);
    u16* hs_w = hs + ((t & 1) ^ 1) * (3 * SPL);

    f32x4 acc = do_mm<R>(hs_r, b, lk, w0r, w1r, w2r);

    if constexpr (R == 3) {
      const float* ip = inp_b + t * 4;
      float i0 = ip[0], i1 = ip[1], i2 = ip[2], i3 = ip[3];
#pragma unroll
      for (int rr = 0; rr < 4; ++rr)
        acc[rr] += i0 * winreg[0][rr] + i1 * winreg[1][rr] + i2 * winreg[2][rr] + i3 * winreg[3][rr];
    }

    f32x4 hnew;
#pragma unroll
    for (int rr = 0; rr < 4; ++rr)
      hnew[rr] = fmaxf(0.0f, 0.9f * hprev[rr] + 0.1f * acc[rr]);
    hprev = hnew;

    *(f32x4*)(rnn_b + (long)t * H5 + j0 + hi * 4) = hnew;

    if (t < TT - 1) {
      u16x4 s0, s1, s2;
#pragma unroll
      for (int rr = 0; rr < 4; ++rr) {
        float v = hnew[rr];
        u16 c0 = f2b(v);  float r1 = v - b2f(c0);
        u16 c1 = f2b(r1); float r2 = r1 - b2f(c1);
        s0[rr] = c0; s1[rr] = c1; s2[rr] = f2b(r2);
      }
      u16* hw = hs_w + (long)b * H5 + j0 + hi * 4;
      sth(hw, s0);
      sth(hw + SPL, s1);
      sth(hw + 2 * SPL, s2);

      // --- fence-free grid barrier: drain write-through stores, bump, poll ---
      asm volatile("s_waitcnt vmcnt(0)" ::: "memory");
      __syncthreads();
      if (threadIdx.x == 0) {
        unsigned old;
        asm volatile("global_atomic_add %0, %1, %2, off sc0 sc1\n\t"
                     "s_waitcnt vmcnt(0)"
                     : "=v"(old) : "v"(ca), "v"(1u) : "memory");
        const unsigned target = (unsigned)(t + 1) * NBLK;
        for (;;) {
          unsigned cur;
          asm volatile("global_load_dword %0, %1, off sc0 sc1\n\t"
                       "s_waitcnt vmcnt(0)"
                       : "=v"(cur) : "v"(ca) : "memory");
          if (cur >= target) break;
          __builtin_amdgcn_s_sleep(1);
        }
      }
      __syncthreads();
    } else {
      float* hl = hn_last + (long)b * H5 + j0 + hi * 4;
#pragma unroll
      for (int rr = 0; rr < 4; ++rr) hl[rr] = hnew[rr];
    }
  }
}

__global__ void __launch_bounds__(256, 1)
rnn_pers(const float* __restrict__ inp, const float* __restrict__ hn,
         const u16* __restrict__ W0, const u16* __restrict__ W1, const u16* __restrict__ W2,
         u16* __restrict__ hs, float* __restrict__ rnn, float* __restrict__ hn_last,
         const float* __restrict__ Win, unsigned* __restrict__ counter) {
  const int lane = threadIdx.x & 63;
  const int lr = lane & 15, hi = lane >> 4, lk = hi * 8;
  const int jt = blockIdx.x;        // 0..79
  const int bt = threadIdx.x >> 6;  // wave id = b-tile
  const int j0 = jt << 4;
  const int b = (bt << 4) + lr;
  float* rnn_b = rnn + (long)b * TT * H5;
  const float* inp_b = inp + (long)b * TT * 4;
  switch (jt >> 4) {
    case 0: pers_loop<0>(j0, b, lr, hi, lk, inp_b, hn, W0, W1, W2, hs, rnn_b, hn_last, Win, counter); break;
    case 1: pers_loop<1>(j0, b, lr, hi, lk, inp_b, hn, W0, W1, W2, hs, rnn_b, hn_last, Win, counter); break;
    case 2: pers_loop<2>(j0, b, lr, hi, lk, inp_b, hn, W0, W1, W2, hs, rnn_b, hn_last, Win, counter); break;
    case 3: pers_loop<3>(j0, b, lr, hi, lk, inp_b, hn, W0, W1, W2, hs, rnn_b, hn_last, Win, counter); break;
    default: pers_loop<4>(j0, b, lr, hi, lk, inp_b, hn, W0, W1, W2, hs, rnn_b, hn_last, Win, counter); break;
  }
}

// ---------------- fallback: one kernel per timestep -------------------------
template <int R>
__device__ void step_one(int t, int j0, int b, int lr, int hi, int lk,
                         const float* __restrict__ inp_b, const float* __restrict__ hn,
                         const u16* __restrict__ W0, const u16* __restrict__ W1,
                         const u16* __restrict__ W2, u16* __restrict__ hs,
                         float* __restrict__ rnn, float* __restrict__ rnn_b,
                         float* __restrict__ hn_last, const float* __restrict__ Win) {
  const long jrow = (long)(j0 + lr) * H5 + lk;
  const u16* hs_r = hs + (t & 1) * (3 * SPL);
  u16* hs_w = hs + ((t & 1) ^ 1) * (3 * SPL);

  f32x4 acc = do_mm<R>(hs_r, b, lk, W0 + jrow, W1 + jrow, W2 + jrow);

  if constexpr (R == 3) {
    float winreg[4][4];
#pragma unroll
    for (int i = 0; i < 4; ++i)
#pragma unroll
      for (int rr = 0; rr < 4; ++rr)
        winreg[i][rr] = Win[i * 256 + (j0 - 768) + hi * 4 + rr];
    const float* ip = inp_b + t * 4;
    float i0 = ip[0], i1 = ip[1], i2 = ip[2], i3 = ip[3];
#pragma unroll
    for (int rr = 0; rr < 4; ++rr)
      acc[rr] += i0 * winreg[0][rr] + i1 * winreg[1][rr] + i2 * winreg[2][rr] + i3 * winreg[3][rr];
  }

  f32x4 hprev;
  {
    const float* hp = (t == 0) ? (hn + (long)b * H5 + j0 + hi * 4)
                               : (rnn + ((long)b * TT + (t - 1)) * H5 + j0 + hi * 4);
#pragma unroll
    for (int rr = 0; rr < 4; ++rr) hprev[rr] = hp[rr];
  }
  f32x4 hnew;
#pragma unroll
  for (int rr = 0; rr < 4; ++rr)
    hnew[rr] = fmaxf(0.0f, 0.9f * hprev[rr] + 0.1f * acc[rr]);

  *(f32x4*)(rnn_b + (long)t * H5 + j0 + hi * 4) = hnew;
  if (t < TT - 1) {
    u16x4 s0, s1, s2;
#pragma unroll
    for (int rr = 0; rr < 4; ++rr) {
      float v = hnew[rr];
      u16 c0 = f2b(v);  float r1 = v - b2f(c0);
      u16 c1 = f2b(r1); float r2 = r1 - b2f(c1);
      s0[rr] = c0; s1[rr] = c1; s2[rr] = f2b(r2);
    }
    u16* hw = hs_w + (long)b * H5 + j0 + hi * 4;
    sth(hw, s0);
    sth(hw + SPL, s1);
    sth(hw + 2 * SPL, s2);
  } else {
    float* hl = hn_last + (long)b * H5 + j0 + hi * 4;
#pragma unroll
    for (int rr = 0; rr < 4; ++rr) hl[rr] = hnew[rr];
  }
}

__global__ void __launch_bounds__(256, 1)
rnn_step(const float* __restrict__ inp, const float* __restrict__ hn,
         const u16* __restrict__ W0, const u16* __restrict__ W1, const u16* __restrict__ W2,
         u16* __restrict__ hs, float* __restrict__ rnn, float* __restrict__ hn_last,
         const float* __restrict__ Win, int t) {
  const int lane = threadIdx.x & 63;
  const int lr = lane & 15, hi = lane >> 4, lk = hi * 8;
  const int jt = blockIdx.x;
  const int bt = threadIdx.x >> 6;
  const int j0 = jt << 4;
  const int b = (bt << 4) + lr;
  float* rnn_b = rnn + (long)b * TT * H5;
  const float* inp_b = inp + (long)b * TT * 4;
  switch (jt >> 4) {
    case 0: step_one<0>(t, j0, b, lr, hi, lk, inp_b, hn, W0, W1, W2, hs, rnn, rnn_b, hn_last, Win); break;
    case 1: step_one<1>(t, j0, b, lr, hi, lk, inp_b, hn, W0, W1, W2, hs, rnn, rnn_b, hn_last, Win); break;
    case 2: step_one<2>(t, j0, b, lr, hi, lk, inp_b, hn, W0, W1, W2, hs, rnn, rnn_b, hn_last, Win); break;
    case 3: step_one<3>(t, j0, b, lr, hi, lk, inp_b, hn, W0, W1, W2, hs, rnn, rnn_b, hn_last, Win); break;
    default: step_one<4>(t, j0, b, lr, hi, lk, inp_b, hn, W0, W1, W2, hs, rnn, rnn_b, hn_last, Win); break;
  }
}

extern "C" void kernel_launch(void* const* d_in, const int* in_sizes, int n_in,
                              void* d_out, int out_size, void* d_ws, size_t ws_size,
                              hipStream_t stream) {
  const float* inp        = (const float*)d_in[0];
  const float* hn         = (const float*)d_in[1];
  const float* w_str2snr  = (const float*)d_in[3];
  const float* w_m12m1    = (const float*)d_in[4];
  const float* w_m12str   = (const float*)d_in[5];
  const float* w_thal2m1  = (const float*)d_in[6];
  const float* w_m12thal  = (const float*)d_in[7];
  const float* w_thal2str = (const float*)d_in[8];
  const float* w_str2stn  = (const float*)d_in[9];
  const float* w_snr2thal = (const float*)d_in[11];
  const float* inp_weight = (const float*)d_in[12];
  const float* mean_b     = (const float*)d_in[14];
  const float* std_b      = (const float*)d_in[16];
  const float* fixedw     = (const float*)d_in[18];

  char* ws = (char*)d_ws;
  u16* W0 = (u16*)(ws + OFF_W0);
  u16* W1 = (u16*)(ws + OFF_W1);
  u16* W2 = (u16*)(ws + OFF_W2);
  u16* hsb = (u16*)(ws + OFF_HS);
  float* Win = (float*)(ws + OFF_WIN);
  unsigned* cnt = (unsigned*)(ws + OFF_CNT);

  float* out = (float*)d_out;
  float* rnn = out + 65536;
  float* hnl = out + 65536 + 41943040;

  hipMemsetAsync(cnt, 0, 128, stream);
  build_w<<<6400, 256, 0, stream>>>(w_str2snr, w_m12m1, w_m12str, w_thal2m1, w_m12thal,
                                    w_thal2str, w_str2stn, w_snr2thal, fixedw, W0, W1, W2);
  build_misc<<<581, 256, 0, stream>>>(hn, inp_weight, mean_b, std_b, out, hsb, Win);

  void* args[] = {(void*)&inp, (void*)&hn, (void*)&W0, (void*)&W1, (void*)&W2, (void*)&hsb,
                  (void*)&rnn, (void*)&hnl, (void*)&Win, (void*)&cnt};
  hipError_t e = hipLaunchCooperativeKernel((const void*)rnn_pers, dim3(NBLK), dim3(256),
                                            args, 0, stream);
  if (e != hipSuccess) {
    for (int t = 0; t < TT; ++t)
      rnn_step<<<NBLK, 256, 0, stream>>>(inp, hn, W0, W1, W2, hsb, rnn, hnl, Win, t);
  }
}

// Round 6
// 8958.797 us; speedup vs baseline: 1.1387x; 1.1387x over previous
//
#include <hip/hip_runtime.h>

typedef unsigned short u16;
typedef unsigned long long u64;
typedef __bf16 v8bf __attribute__((ext_vector_type(8)));
typedef float f32x4 __attribute__((ext_vector_type(4)));
typedef u16 u16x4 __attribute__((ext_vector_type(4)));

#define H5 1280
#define TT 512
#define NBLK 80
#define GBLK 20   // blocks per independent batch-group
#define SPL 81920 // u16 elems per split buffer (64*1280)

// ws layout (bytes)
#define OFF_W0 0
#define OFF_W1 3276800
#define OFF_W2 6553600
#define OFF_HS 9830400   // u16 [2][3][64][1280]
#define OFF_WIN 10813440 // float [4][256]
#define OFF_CNT 10817536 // barrier counters (4 groups)

#define MFMA(a, b, c) __builtin_amdgcn_mfma_f32_16x16x32_bf16(a, b, c, 0, 0, 0)

__device__ __forceinline__ float htanh_(float x) {
  return fminf(fmaxf(x, 1e-10f), 1.0f);
}
__device__ __forceinline__ u16 f2b(float f) {
  unsigned u = __float_as_uint(f);
  return (u16)((u + 0x7fffu + ((u >> 16) & 1u)) >> 16);  // RNE
}
__device__ __forceinline__ float b2f(u16 b) {
  return __uint_as_float(((unsigned)b) << 16);
}

// agent-coherent 16B load, async issue — caller batches then does ONE
// s_waitcnt vmcnt(0) + sched_barrier(0) before any consumer (rule #18).
__device__ __forceinline__ v8bf ldh16(const u16* p) {
  v8bf v;
  asm volatile("global_load_dwordx4 %0, %1, off sc0 sc1" : "=v"(v) : "v"(p) : "memory");
  return v;
}
// agent-coherent 8B store (write-through to coherence point)
__device__ __forceinline__ void sth(u16* p, u16x4 v) {
  union { u16x4 s; u64 q; } u;
  u.s = v;
  __hip_atomic_store((u64*)p, u.q, __ATOMIC_RELAXED, __HIP_MEMORY_SCOPE_AGENT);
}

// ---------------- prep: effective W_rec, 3-way bf16 split -------------------
__global__ void build_w(const float* __restrict__ w_str2snr, const float* __restrict__ w_m12m1,
                        const float* __restrict__ w_m12str, const float* __restrict__ w_thal2m1,
                        const float* __restrict__ w_m12thal, const float* __restrict__ w_thal2str,
                        const float* __restrict__ w_str2stn, const float* __restrict__ w_snr2thal,
                        const float* __restrict__ fixedw, u16* __restrict__ W0,
                        u16* __restrict__ W1, u16* __restrict__ W2) {
  int idx = blockIdx.x * 256 + threadIdx.x;  // j*1280 + k
  if (idx >= H5 * H5) return;
  int j = idx / H5, k = idx - j * H5;
  int jr = j >> 8, kr = k >> 8, kk = k & 255;
  int o = (j & 255) * 256 + kk;
  float w = 0.0f;
  if (jr == 0) {
    if (kr == 0) w = -fixedw[o];  // str2str_mask==0 -> -(fixed)
    else if (kr == 3) w = htanh_(w_thal2str[o]);
    else if (kr == 4) w = (kk < 180) ? htanh_(w_m12str[o]) : 0.0f;  // n_inhib=76
  } else if (jr == 1) {
    if (kr == 0) w = (kk >= 128) ? htanh_(w_str2stn[o]) : 0.0f;
  } else if (jr == 2) {
    if (kr == 0) w = (kk < 128) ? -htanh_(w_str2snr[o]) : 0.0f;
    else if (kr == 1) w = -htanh_(w_str2stn[o]);  // faithful: str2stn weight
  } else if (jr == 3) {
    if (kr == 2) w = -htanh_(w_snr2thal[o]);
    else if (kr == 4) w = htanh_(w_m12thal[o]);
  } else {
    if (kr == 3) w = htanh_(w_thal2m1[o]);
    else if (kr == 4) w = (kk < 180) ? htanh_(w_m12m1[o]) : -htanh_(w_m12m1[o]);
  }
  u16 c0 = f2b(w);  float r1 = w - b2f(c0);
  u16 c1 = f2b(r1); float r2 = r1 - b2f(c1);
  u16 c2 = f2b(r2);
  W0[idx] = c0; W1[idx] = c1; W2[idx] = c2;
}

// ---------------- prep: mean/std out, h0 splits, Win ------------------------
__global__ void build_misc(const float* __restrict__ hn, const float* __restrict__ inp_weight,
                           const float* __restrict__ mean_b, const float* __restrict__ std_b,
                           float* __restrict__ out, u16* __restrict__ hs, float* __restrict__ Win) {
  int gid = blockIdx.x * 256 + threadIdx.x;
  if (gid < 65536) {
    out[gid] = (gid < 32768) ? mean_b[0] : fminf(10.0f, fmaxf(-5.0f, std_b[0]));
  } else if (gid < 65536 + SPL) {
    int i = gid - 65536;
    float v = hn[i];
    u16 c0 = f2b(v);  float r1 = v - b2f(c0);
    u16 c1 = f2b(r1); float r2 = r1 - b2f(c1);
    u16 c2 = f2b(r2);
    hs[i] = c0; hs[SPL + i] = c1; hs[2 * SPL + i] = c2;
  } else if (gid < 65536 + SPL + 1024) {
    int i = gid - 65536 - SPL;
    Win[i] = htanh_(inp_weight[(i >> 8) * H5 + 768 + (i & 255)]);
  }
}

// ---------------- compile-time region configs -------------------------------
template <int R> struct RC;
template <> struct RC<0> { static constexpr int kb[3] = {0, 768, 1024}; static constexpr int nch[3] = {8, 8, 8}; };
template <> struct RC<1> { static constexpr int kb[3] = {128, 0, 0};    static constexpr int nch[3] = {4, 0, 0}; };
template <> struct RC<2> { static constexpr int kb[3] = {0, 256, 0};    static constexpr int nch[3] = {4, 8, 0}; };
template <> struct RC<3> { static constexpr int kb[3] = {512, 1024, 0}; static constexpr int nch[3] = {8, 8, 0}; };
template <> struct RC<4> { static constexpr int kb[3] = {768, 1024, 0}; static constexpr int nch[3] = {8, 8, 0}; };

// One step's matmul. Per k-group: batch-issue all h split loads (<=24 asm
// dwordx4, <=96 VGPR live), one vmcnt(0)+sched_barrier, then MFMAs with
// plain (L2-hit) W loads.
template <int R>
__device__ __forceinline__ f32x4 do_mm(const u16* __restrict__ hs_r, int b, int lk,
                                       const u16* __restrict__ w0r, const u16* __restrict__ w1r,
                                       const u16* __restrict__ w2r) {
  f32x4 A00 = {0.f, 0.f, 0.f, 0.f}, A01 = {0.f, 0.f, 0.f, 0.f}, A02 = {0.f, 0.f, 0.f, 0.f};
  f32x4 A10 = {0.f, 0.f, 0.f, 0.f}, A11 = {0.f, 0.f, 0.f, 0.f}, A20 = {0.f, 0.f, 0.f, 0.f};
#pragma unroll
  for (int q = 0; q < 3; ++q) {
    if (RC<R>::nch[q] > 0) {
      const int kbq = RC<R>::kb[q];
      const u16* hb = hs_r + (long)b * H5 + kbq + lk;
      v8bf h0[8], h1[8], h2[8];
#pragma unroll
      for (int c = 0; c < RC<R>::nch[q]; ++c) {
        h0[c] = ldh16(hb + c * 32);
        h1[c] = ldh16(hb + SPL + c * 32);
        h2[c] = ldh16(hb + 2 * SPL + c * 32);
      }
      asm volatile("s_waitcnt vmcnt(0)" ::: "memory");
      __builtin_amdgcn_sched_barrier(0);
#pragma unroll
      for (int c = 0; c < RC<R>::nch[q]; ++c) {
        v8bf a0 = *(const v8bf*)(w0r + kbq + c * 32);
        v8bf a1 = *(const v8bf*)(w1r + kbq + c * 32);
        v8bf a2 = *(const v8bf*)(w2r + kbq + c * 32);
        // 6-term split product: W0h0+W0h1+W0h2 + W1h0+W1h1 + W2h0
        A00 = MFMA(a0, h0[c], A00);
        A01 = MFMA(a0, h1[c], A01);
        A02 = MFMA(a0, h2[c], A02);
        A10 = MFMA(a1, h0[c], A10);
        A11 = MFMA(a1, h1[c], A11);
        A20 = MFMA(a2, h0[c], A20);
      }
    }
  }
  f32x4 acc;
#pragma unroll
  for (int rr = 0; rr < 4; ++rr)
    acc[rr] = ((A00[rr] + A10[rr]) + (A01[rr] + A11[rr])) + (A02[rr] + A20[rr]);
  return acc;
}

// ---------------- persistent cooperative worker (per region) ----------------
// Groups of 16 batch columns are fully independent: each group of GBLK blocks
// barriers only among itself on its own counter line.
template <int R>
__device__ void pers_loop(int j0, int b, int lr, int hi, int lk,
                          const float* __restrict__ inp_b, const float* __restrict__ hn,
                          const u16* __restrict__ W0, const u16* __restrict__ W1,
                          const u16* __restrict__ W2, u16* __restrict__ hs,
                          float* __restrict__ rnn_b, float* __restrict__ hn_last,
                          const float* __restrict__ Win, unsigned* __restrict__ ctr) {
  const long jrow = (long)(j0 + lr) * H5 + lk;
  const u16* w0r = W0 + jrow;
  const u16* w1r = W1 + jrow;
  const u16* w2r = W2 + jrow;

  float winreg[4][4];
  if constexpr (R == 3) {
#pragma unroll
    for (int i = 0; i < 4; ++i)
#pragma unroll
      for (int rr = 0; rr < 4; ++rr)
        winreg[i][rr] = Win[i * 256 + (j0 - 768) + hi * 4 + rr];
  }

  f32x4 hprev;
  {
    const float* hp = hn + (long)b * H5 + j0 + hi * 4;
#pragma unroll
    for (int rr = 0; rr < 4; ++rr) hprev[rr] = hp[rr];
  }

  const u64 ca = (u64)ctr;

  for (int t = 0; t < TT; ++t) {
    const u16* hs_r = hs + (t & 1) * (3 * SPL);
    u16* hs_w = hs + ((t & 1) ^ 1) * (3 * SPL);

    f32x4 acc = do_mm<R>(hs_r, b, lk, w0r, w1r, w2r);

    if constexpr (R == 3) {
      const float* ip = inp_b + t * 4;
      float i0 = ip[0], i1 = ip[1], i2 = ip[2], i3 = ip[3];
#pragma unroll
      for (int rr = 0; rr < 4; ++rr)
        acc[rr] += i0 * winreg[0][rr] + i1 * winreg[1][rr] + i2 * winreg[2][rr] + i3 * winreg[3][rr];
    }

    f32x4 hnew;
#pragma unroll
    for (int rr = 0; rr < 4; ++rr)
      hnew[rr] = fmaxf(0.0f, 0.9f * hprev[rr] + 0.1f * acc[rr]);
    hprev = hnew;

    *(f32x4*)(rnn_b + (long)t * H5 + j0 + hi * 4) = hnew;

    if (t < TT - 1) {
      u16x4 s0, s1, s2;
#pragma unroll
      for (int rr = 0; rr < 4; ++rr) {
        float v = hnew[rr];
        u16 c0 = f2b(v);  float r1 = v - b2f(c0);
        u16 c1 = f2b(r1); float r2 = r1 - b2f(c1);
        s0[rr] = c0; s1[rr] = c1; s2[rr] = f2b(r2);
      }
      u16* hw = hs_w + (long)b * H5 + j0 + hi * 4;
      sth(hw, s0);
      sth(hw + SPL, s1);
      sth(hw + 2 * SPL, s2);

      // --- fence-free per-group barrier (validated protocol, r2/r3/r5) ---
      asm volatile("s_waitcnt vmcnt(0)" ::: "memory");
      __syncthreads();
      if (threadIdx.x == 0) {
        unsigned old;
        asm volatile("global_atomic_add %0, %1, %2, off sc0 sc1\n\t"
                     "s_waitcnt vmcnt(0)"
                     : "=v"(old) : "v"(ca), "v"(1u) : "memory");
        const unsigned target = (unsigned)(t + 1) * GBLK;
        for (;;) {
          unsigned cur;
          asm volatile("global_load_dword %0, %1, off sc0 sc1\n\t"
                       "s_waitcnt vmcnt(0)"
                       : "=v"(cur) : "v"(ca) : "memory");
          if (cur >= target) break;
          __builtin_amdgcn_s_sleep(2);
        }
      }
      __syncthreads();
    } else {
      float* hl = hn_last + (long)b * H5 + j0 + hi * 4;
#pragma unroll
      for (int rr = 0; rr < 4; ++rr) hl[rr] = hnew[rr];
    }
  }
}

__global__ void __launch_bounds__(256, 1)
rnn_pers(const float* __restrict__ inp, const float* __restrict__ hn,
         const u16* __restrict__ W0, const u16* __restrict__ W1, const u16* __restrict__ W2,
         u16* __restrict__ hs, float* __restrict__ rnn, float* __restrict__ hn_last,
         const float* __restrict__ Win, unsigned* __restrict__ cnt, int cstride) {
  const int lane = threadIdx.x & 63;
  const int lr = lane & 15, hi = lane >> 4, lk = hi * 8;
  const int g = blockIdx.x & 3;   // batch group (16 cols); bx&3 biases group
  const int i = blockIdx.x >> 2;  // 0..19 within group (XCD round-robin pairs)
  const int w = threadIdx.x >> 6; // wave id = local j-tile
  const int jt = i * 4 + w;       // 0..79 (4 consecutive j-tiles per block,
  const int j0 = jt << 4;         //   all in one region since 16%4==0)
  const int b = (g << 4) + lr;
  unsigned* ctr = cnt + g * cstride;
  float* rnn_b = rnn + (long)b * TT * H5;
  const float* inp_b = inp + (long)b * TT * 4;
  switch (i >> 2) {
    case 0: pers_loop<0>(j0, b, lr, hi, lk, inp_b, hn, W0, W1, W2, hs, rnn_b, hn_last, Win, ctr); break;
    case 1: pers_loop<1>(j0, b, lr, hi, lk, inp_b, hn, W0, W1, W2, hs, rnn_b, hn_last, Win, ctr); break;
    case 2: pers_loop<2>(j0, b, lr, hi, lk, inp_b, hn, W0, W1, W2, hs, rnn_b, hn_last, Win, ctr); break;
    case 3: pers_loop<3>(j0, b, lr, hi, lk, inp_b, hn, W0, W1, W2, hs, rnn_b, hn_last, Win, ctr); break;
    default: pers_loop<4>(j0, b, lr, hi, lk, inp_b, hn, W0, W1, W2, hs, rnn_b, hn_last, Win, ctr); break;
  }
}

// ---------------- fallback: one kernel per timestep -------------------------
template <int R>
__device__ void step_one(int t, int j0, int b, int lr, int hi, int lk,
                         const float* __restrict__ inp_b, const float* __restrict__ hn,
                         const u16* __restrict__ W0, const u16* __restrict__ W1,
                         const u16* __restrict__ W2, u16* __restrict__ hs,
                         float* __restrict__ rnn, float* __restrict__ rnn_b,
                         float* __restrict__ hn_last, const float* __restrict__ Win) {
  const long jrow = (long)(j0 + lr) * H5 + lk;
  const u16* hs_r = hs + (t & 1) * (3 * SPL);
  u16* hs_w = hs + ((t & 1) ^ 1) * (3 * SPL);

  f32x4 acc = do_mm<R>(hs_r, b, lk, W0 + jrow, W1 + jrow, W2 + jrow);

  if constexpr (R == 3) {
    float winreg[4][4];
#pragma unroll
    for (int i = 0; i < 4; ++i)
#pragma unroll
      for (int rr = 0; rr < 4; ++rr)
        winreg[i][rr] = Win[i * 256 + (j0 - 768) + hi * 4 + rr];
    const float* ip = inp_b + t * 4;
    float i0 = ip[0], i1 = ip[1], i2 = ip[2], i3 = ip[3];
#pragma unroll
    for (int rr = 0; rr < 4; ++rr)
      acc[rr] += i0 * winreg[0][rr] + i1 * winreg[1][rr] + i2 * winreg[2][rr] + i3 * winreg[3][rr];
  }

  f32x4 hprev;
  {
    const float* hp = (t == 0) ? (hn + (long)b * H5 + j0 + hi * 4)
                               : (rnn + ((long)b * TT + (t - 1)) * H5 + j0 + hi * 4);
#pragma unroll
    for (int rr = 0; rr < 4; ++rr) hprev[rr] = hp[rr];
  }
  f32x4 hnew;
#pragma unroll
  for (int rr = 0; rr < 4; ++rr)
    hnew[rr] = fmaxf(0.0f, 0.9f * hprev[rr] + 0.1f * acc[rr]);

  *(f32x4*)(rnn_b + (long)t * H5 + j0 + hi * 4) = hnew;
  if (t < TT - 1) {
    u16x4 s0, s1, s2;
#pragma unroll
    for (int rr = 0; rr < 4; ++rr) {
      float v = hnew[rr];
      u16 c0 = f2b(v);  float r1 = v - b2f(c0);
      u16 c1 = f2b(r1); float r2 = r1 - b2f(c1);
      s0[rr] = c0; s1[rr] = c1; s2[rr] = f2b(r2);
    }
    u16* hw = hs_w + (long)b * H5 + j0 + hi * 4;
    sth(hw, s0);
    sth(hw + SPL, s1);
    sth(hw + 2 * SPL, s2);
  } else {
    float* hl = hn_last + (long)b * H5 + j0 + hi * 4;
#pragma unroll
    for (int rr = 0; rr < 4; ++rr) hl[rr] = hnew[rr];
  }
}

__global__ void __launch_bounds__(256, 1)
rnn_step(const float* __restrict__ inp, const float* __restrict__ hn,
         const u16* __restrict__ W0, const u16* __restrict__ W1, const u16* __restrict__ W2,
         u16* __restrict__ hs, float* __restrict__ rnn, float* __restrict__ hn_last,
         const float* __restrict__ Win, int t) {
  const int lane = threadIdx.x & 63;
  const int lr = lane & 15, hi = lane >> 4, lk = hi * 8;
  const int g = blockIdx.x & 3;
  const int i = blockIdx.x >> 2;
  const int w = threadIdx.x >> 6;
  const int jt = i * 4 + w;
  const int j0 = jt << 4;
  const int b = (g << 4) + lr;
  float* rnn_b = rnn + (long)b * TT * H5;
  const float* inp_b = inp + (long)b * TT * 4;
  switch (i >> 2) {
    case 0: step_one<0>(t, j0, b, lr, hi, lk, inp_b, hn, W0, W1, W2, hs, rnn, rnn_b, hn_last, Win); break;
    case 1: step_one<1>(t, j0, b, lr, hi, lk, inp_b, hn, W0, W1, W2, hs, rnn, rnn_b, hn_last, Win); break;
    case 2: step_one<2>(t, j0, b, lr, hi, lk, inp_b, hn, W0, W1, W2, hs, rnn, rnn_b, hn_last, Win); break;
    case 3: step_one<3>(t, j0, b, lr, hi, lk, inp_b, hn, W0, W1, W2, hs, rnn, rnn_b, hn_last, Win); break;
    default: step_one<4>(t, j0, b, lr, hi, lk, inp_b, hn, W0, W1, W2, hs, rnn, rnn_b, hn_last, Win); break;
  }
}

extern "C" void kernel_launch(void* const* d_in, const int* in_sizes, int n_in,
                              void* d_out, int out_size, void* d_ws, size_t ws_size,
                              hipStream_t stream) {
  const float* inp        = (const float*)d_in[0];
  const float* hn         = (const float*)d_in[1];
  const float* w_str2snr  = (const float*)d_in[3];
  const float* w_m12m1    = (const float*)d_in[4];
  const float* w_m12str   = (const float*)d_in[5];
  const float* w_thal2m1  = (const float*)d_in[6];
  const float* w_m12thal  = (const float*)d_in[7];
  const float* w_thal2str = (const float*)d_in[8];
  const float* w_str2stn  = (const float*)d_in[9];
  const float* w_snr2thal = (const float*)d_in[11];
  const float* inp_weight = (const float*)d_in[12];
  const float* mean_b     = (const float*)d_in[14];
  const float* std_b      = (const float*)d_in[16];
  const float* fixedw     = (const float*)d_in[18];

  char* ws = (char*)d_ws;
  u16* W0 = (u16*)(ws + OFF_W0);
  u16* W1 = (u16*)(ws + OFF_W1);
  u16* W2 = (u16*)(ws + OFF_W2);
  u16* hsb = (u16*)(ws + OFF_HS);
  float* Win = (float*)(ws + OFF_WIN);
  unsigned* cnt = (unsigned*)(ws + OFF_CNT);

  // Per-group counters spread across distinct cachelines if scratch allows
  // (ws >= OFF_CNT+1024 proven risky to assume; branch on actual size).
  int cstride;     // in u32 units
  size_t cbytes;
  if (ws_size >= (size_t)OFF_CNT + 1024) { cstride = 64; cbytes = 1024; }  // 256B apart
  else                                   { cstride = 8;  cbytes = 128;  }  // packed (known-safe)

  float* out = (float*)d_out;
  float* rnn = out + 65536;
  float* hnl = out + 65536 + 41943040;

  hipMemsetAsync(cnt, 0, cbytes, stream);
  build_w<<<6400, 256, 0, stream>>>(w_str2snr, w_m12m1, w_m12str, w_thal2m1, w_m12thal,
                                    w_thal2str, w_str2stn, w_snr2thal, fixedw, W0, W1, W2);
  build_misc<<<581, 256, 0, stream>>>(hn, inp_weight, mean_b, std_b, out, hsb, Win);

  void* args[] = {(void*)&inp, (void*)&hn, (void*)&W0, (void*)&W1, (void*)&W2, (void*)&hsb,
                  (void*)&rnn, (void*)&hnl, (void*)&Win, (void*)&cnt, (void*)&cstride};
  hipError_t e = hipLaunchCooperativeKernel((const void*)rnn_pers, dim3(NBLK), dim3(256),
                                            args, 0, stream);
  if (e != hipSuccess) {
    for (int t = 0; t < TT; ++t)
      rnn_step<<<NBLK, 256, 0, stream>>>(inp, hn, W0, W1, W2, hsb, rnn, hnl, Win, t);
  }
}